// Round 3
// baseline (511.771 us; speedup 1.0000x reference)
//
#include <hip/hip_runtime.h>

// Problem constants (B=32, N=16384, C=128, fp32 everywhere)
#define ROWS   524288LL        // B*N
#define OUT_ELEMS 67108864LL   // B*N*C
#define CCOLS  128

// ---------------------------------------------------------------------------
// Pass 1: per row r, d1 = x[r].theta1, d2 = x[r].theta2,
//         attenU[r] = exp(W * tanh(d1) * sigmoid(d2)); global sum via
//         block-reduced atomicAdd into ws accumulator.
// Layout: one wave handles a PAIR of rows per iteration:
//         64 lanes x float4 = 256 floats = rows 2p (lanes 0-31) and 2p+1
//         (lanes 32-63). Fully coalesced 1 KiB per wave-load.
// ---------------------------------------------------------------------------
__global__ __launch_bounds__(256) void gated_pass1(
    const float* __restrict__ x,
    const float* __restrict__ th1,
    const float* __restrict__ th2,
    const float* __restrict__ Wp,
    float* __restrict__ attenU,     // d_out + OUT_ELEMS (unnormalized for now)
    float* __restrict__ sumAcc)     // d_ws[0]
{
    const int lane  = threadIdx.x & 63;
    const int wid   = (blockIdx.x * blockDim.x + threadIdx.x) >> 6;
    const int nwave = (gridDim.x * blockDim.x) >> 6;
    const int col4  = lane & 31;    // float4 column index within the row

    const float4 t1 = reinterpret_cast<const float4*>(th1)[col4];
    const float4 t2 = reinterpret_cast<const float4*>(th2)[col4];
    const float  W  = Wp[0];

    const float4* __restrict__ x4 = reinterpret_cast<const float4*>(x);
    const int nPairs = (int)(ROWS / 2);   // 262144

    float localSum = 0.0f;

    for (int p = wid; p < nPairs; p += nwave) {
        float4 v = x4[(long long)p * 64 + lane];
        float d1 = v.x * t1.x + v.y * t1.y + v.z * t1.z + v.w * t1.w;
        float d2 = v.x * t2.x + v.y * t2.y + v.z * t2.z + v.w * t2.w;
        // reduce within each 32-lane half (masks < 32 never cross the split)
        #pragma unroll
        for (int m = 16; m; m >>= 1) {
            d1 += __shfl_xor(d1, m);
            d2 += __shfl_xor(d2, m);
        }
        if ((lane & 31) == 0) {
            int row   = p * 2 + (lane >> 5);
            float th  = tanhf(d1);
            float sg  = 1.0f / (1.0f + expf(-d2));
            float a   = expf(W * th * sg);
            attenU[row] = a;
            localSum += a;
        }
    }

    // only lanes 0 and 32 hold nonzero partials; fold halves then block-reduce
    localSum += __shfl_xor(localSum, 32);
    __shared__ float wsum[4];
    if ((threadIdx.x & 63) == 0) wsum[threadIdx.x >> 6] = localSum;
    __syncthreads();
    if (threadIdx.x == 0) {
        float s = wsum[0] + wsum[1] + wsum[2] + wsum[3];
        atomicAdd(sumAcc, s);
    }
}

// ---------------------------------------------------------------------------
// Pass 1b: normalize atten in place (separate kernel -> no read/write race
// with the out-scaling readers). Tiny: 2 MiB read + 2 MiB write.
// Uses true division so atten matches the reference rounding exactly.
// ---------------------------------------------------------------------------
__global__ __launch_bounds__(256) void gated_norm(
    float* __restrict__ atten,
    const float* __restrict__ sumAcc)
{
    const float S = sumAcc[0];
    const int n4 = (int)(ROWS / 4);     // 131072
    int i = blockIdx.x * blockDim.x + threadIdx.x;
    float4* a4 = reinterpret_cast<float4*>(atten);
    for (; i < n4; i += gridDim.x * blockDim.x) {
        float4 v = a4[i];
        v.x /= S; v.y /= S; v.z /= S; v.w /= S;
        a4[i] = v;
    }
}

// ---------------------------------------------------------------------------
// Pass 2: out[r, c] = atten[r] * x[r, c]   (atten already normalized)
// float4 grid-stride; 32 consecutive lanes share one atten row -> broadcast.
// ---------------------------------------------------------------------------
__global__ __launch_bounds__(256) void gated_pass2(
    const float* __restrict__ x,
    const float* __restrict__ atten,
    float* __restrict__ out)
{
    const long long n4 = OUT_ELEMS / 4;   // 16777216
    const float4* __restrict__ x4 = reinterpret_cast<const float4*>(x);
    float4* __restrict__ o4 = reinterpret_cast<float4*>(out);
    long long i = (long long)blockIdx.x * blockDim.x + threadIdx.x;
    const long long stride = (long long)gridDim.x * blockDim.x;
    for (; i < n4; i += stride) {
        float a  = atten[i >> 5];         // row = (i*4)/128
        float4 v = x4[i];
        v.x *= a; v.y *= a; v.z *= a; v.w *= a;
        o4[i] = v;
    }
}

extern "C" void kernel_launch(void* const* d_in, const int* in_sizes, int n_in,
                              void* d_out, int out_size, void* d_ws, size_t ws_size,
                              hipStream_t stream) {
    const float* x   = (const float*)d_in[0];
    const float* th1 = (const float*)d_in[1];
    const float* th2 = (const float*)d_in[2];
    const float* W   = (const float*)d_in[3];

    float* out   = (float*)d_out;
    float* atten = out + OUT_ELEMS;       // tuple output #2 lives here
    float* sumAcc = (float*)d_ws;

    // ws is re-poisoned to 0xAA before every launch -> zero the accumulator
    hipMemsetAsync(d_ws, 0, 256, stream);

    gated_pass1<<<2048, 256, 0, stream>>>(x, th1, th2, W, atten, sumAcc);
    gated_norm <<<512,  256, 0, stream>>>(atten, sumAcc);
    gated_pass2<<<2048, 256, 0, stream>>>(x, atten, out);
}

// Round 7
// 495.244 us; speedup vs baseline: 1.0334x; 1.0334x over previous
//
#include <hip/hip_runtime.h>

// Problem constants (B=32, N=16384, C=128, fp32 everywhere)
#define ROWS      524288       // B*N
#define OUT_ELEMS 67108864LL   // B*N*C
#define NBLK1     2048         // pass1 grid; 256 rows per block

// Native clang vector type — required by __builtin_nontemporal_store
// (HIP's float4 is a class and is rejected by the builtin).
typedef float floatx4 __attribute__((ext_vector_type(4)));

// ---------------------------------------------------------------------------
// Pass 1: per row r: d1 = x[r].theta1, d2 = x[r].theta2,
//   attenU[r] = exp(W * tanh(d1) * sigmoid(d2)); per-block partial sums.
// Layout: 16 lanes per row, 2 float4 per lane (= 128 cols). 4 rows per wave
// per iteration, 16 iterations = 64 rows per wave (one batch, no grid-stride).
// Reduced (d1,d2) stashed in LDS so the transcendental block runs once per
// 64 rows with ALL 64 lanes active (vs 2/64 in the previous version).
// ---------------------------------------------------------------------------
__global__ __launch_bounds__(256) void gated_pass1(
    const float* __restrict__ x,
    const float* __restrict__ th1,
    const float* __restrict__ th2,
    const float* __restrict__ Wp,
    float* __restrict__ attenU,      // d_out + OUT_ELEMS (unnormalized)
    float* __restrict__ partials)    // d_ws + 16, one float per block
{
    __shared__ float2 stash[4][64];  // [wave][row-in-batch] = (d1,d2)
    __shared__ float  wsum[4];

    const int lane  = threadIdx.x & 63;
    const int wslot = threadIdx.x >> 6;   // wave index in block (0..3)
    const int g     = lane >> 4;          // row-in-quad (0..3)
    const int sub   = lane & 15;          // 16 lanes per row

    const float4* __restrict__ t1v = reinterpret_cast<const float4*>(th1);
    const float4* __restrict__ t2v = reinterpret_cast<const float4*>(th2);
    const float4 t1a = t1v[sub * 2], t1b = t1v[sub * 2 + 1];
    const float4 t2a = t2v[sub * 2], t2b = t2v[sub * 2 + 1];
    const float  W   = Wp[0];

    const int rowBase = blockIdx.x * 256 + wslot * 64;
    const float4* __restrict__ x4 = reinterpret_cast<const float4*>(x);

    #pragma unroll 4
    for (int it = 0; it < 16; ++it) {
        const int row = rowBase + it * 4 + g;
        const float4 v0 = x4[(size_t)row * 32 + sub * 2];
        const float4 v1 = x4[(size_t)row * 32 + sub * 2 + 1];
        float d1 = v0.x*t1a.x + v0.y*t1a.y + v0.z*t1a.z + v0.w*t1a.w
                 + v1.x*t1b.x + v1.y*t1b.y + v1.z*t1b.z + v1.w*t1b.w;
        float d2 = v0.x*t2a.x + v0.y*t2a.y + v0.z*t2a.z + v0.w*t2a.w
                 + v1.x*t2b.x + v1.y*t2b.y + v1.z*t2b.z + v1.w*t2b.w;
        // 4-step butterfly within each 16-lane group
        #pragma unroll
        for (int m = 8; m; m >>= 1) {
            d1 += __shfl_xor(d1, m);
            d2 += __shfl_xor(d2, m);
        }
        if (sub == 0) stash[wslot][it * 4 + g] = make_float2(d1, d2);
    }
    __syncthreads();

    // Batch phase: one row per lane, all 64 lanes active.
    const float2 s  = stash[wslot][lane];
    const float  th = tanhf(s.x);
    const float  sg = 1.0f / (1.0f + expf(-s.y));
    const float  a  = expf(W * th * sg);
    attenU[rowBase + lane] = a;      // 64 consecutive floats: coalesced

    float ls = a;
    #pragma unroll
    for (int m = 32; m; m >>= 1) ls += __shfl_xor(ls, m);
    if (lane == 0) wsum[wslot] = ls;
    __syncthreads();
    if (threadIdx.x == 0)
        partials[blockIdx.x] = wsum[0] + wsum[1] + wsum[2] + wsum[3];
}

// ---------------------------------------------------------------------------
// Reduce 2048 per-block partials -> S and 1/S. One block; ~3 us.
// ---------------------------------------------------------------------------
__global__ __launch_bounds__(256) void gated_reduce(
    const float* __restrict__ partials,
    float* __restrict__ sOut)        // sOut[0] = S, sOut[1] = 1/S
{
    __shared__ float wsum[4];
    float s = 0.0f;
    for (int i = threadIdx.x; i < NBLK1; i += 256) s += partials[i];
    #pragma unroll
    for (int m = 32; m; m >>= 1) s += __shfl_xor(s, m);
    if ((threadIdx.x & 63) == 0) wsum[threadIdx.x >> 6] = s;
    __syncthreads();
    if (threadIdx.x == 0) {
        const float S = wsum[0] + wsum[1] + wsum[2] + wsum[3];
        sOut[0] = S;
        sOut[1] = 1.0f / S;
    }
}

// ---------------------------------------------------------------------------
// Pass 2: an = attenU[r]/S; out[r,c] = an * x[r,c]; atten[r] = an (fused norm).
// Nontemporal stores for `out` keep x resident in the 256 MiB L3 (x was
// loaded by pass1 and is exactly L3-sized). The atten[row] read-then-write is
// race-free: the 32 lanes owning a row are in one wave; the predicated store
// follows the load in program order.
// ---------------------------------------------------------------------------
__global__ __launch_bounds__(256) void gated_pass2(
    const float* __restrict__ x,
    float* __restrict__ atten,       // in: unnormalized, out: normalized
    float* __restrict__ out,
    const float* __restrict__ sOut)
{
    const float invS = sOut[1];
    const floatx4* __restrict__ x4 = reinterpret_cast<const floatx4*>(x);
    floatx4* __restrict__ o4 = reinterpret_cast<floatx4*>(out);
    const long long n4 = OUT_ELEMS / 4;      // 16777216
    long long i = (long long)blockIdx.x * blockDim.x + threadIdx.x;
    const long long stride = (long long)gridDim.x * blockDim.x;
    for (; i < n4; i += stride) {
        const int row = (int)(i >> 5);       // 32 float4s per row
        const float an = atten[row] * invS;
        floatx4 v = x4[i];
        v *= an;
        __builtin_nontemporal_store(v, &o4[i]);
        if ((i & 31) == 0) atten[row] = an;
    }
}

extern "C" void kernel_launch(void* const* d_in, const int* in_sizes, int n_in,
                              void* d_out, int out_size, void* d_ws, size_t ws_size,
                              hipStream_t stream) {
    const float* x   = (const float*)d_in[0];
    const float* th1 = (const float*)d_in[1];
    const float* th2 = (const float*)d_in[2];
    const float* W   = (const float*)d_in[3];

    float* out      = (float*)d_out;
    float* atten    = out + OUT_ELEMS;     // tuple output #2
    float* sOut     = (float*)d_ws;        // [0]=S, [1]=1/S
    float* partials = sOut + 16;           // 2048 floats, written before read

    gated_pass1 <<<NBLK1, 256, 0, stream>>>(x, th1, th2, W, atten, partials);
    gated_reduce<<<1,     256, 0, stream>>>(partials, sOut);
    gated_pass2 <<<2048,  256, 0, stream>>>(x, atten, out, sOut);
}